// Round 9
// baseline (384.852 us; speedup 1.0000x reference)
//
#include <hip/hip_runtime.h>

// LinearAttention: B=2, L=2048, D=1024, H=16, FD=16, HD=64. fp32 in/out.
// Denominator chain (q,k proj + cumsum + dots) stays fp64 (cancellation).
// v-proj/out-proj: bf16x3-split MFMA GEMMs (A3=[Ahi|Alo|Ahi],
// B3=[Bhi|Bhi|Blo] => Ahi.Bhi+Alo.Bhi+Ahi.Blo).
// q,k proj: R7-proven 64x64/TK=32 fp64 vector GEMM + SPLIT-K=2 (grid z):
// R7 profile showed VALU-bound at 62% busy with only 2 waves/SIMD (grid
// 512); split-K doubles residency. Epilogue = f64 atomicAdd into zeroed
// outputs (2 commutative contributions -> deterministic).
// R8 lesson: do NOT fuse divergent bodies — union regalloc (148 VGPR) +
// 64KB LDS tanked occupancy to 9.5%.

#define L_    2048
#define NROW  4096   // B*L
#define CHUNK 128
#define NCH   16
#define NBH   32
#define K3    3072

#define TM 64
#define TN 64
#define TK 32
#define LDP 68

typedef __attribute__((ext_vector_type(8))) short short8v;
typedef __attribute__((ext_vector_type(4))) float floatx4;

__device__ __forceinline__ ushort bf_rne(float x) {
    unsigned u = __float_as_uint(x);
    return (ushort)((u + 0x7fffu + ((u >> 16) & 1u)) >> 16);
}
__device__ __forceinline__ float bf_to_f(ushort h) {
    return __uint_as_float(((unsigned)h) << 16);
}
__device__ __forceinline__ void gload16(const ushort* g, ushort* l) {
    __builtin_amdgcn_global_load_lds(
        (const __attribute__((address_space(1))) unsigned int*)g,
        (__attribute__((address_space(3))) unsigned int*)l, 16, 0, 0);
}

// ---- split fp32 [rows][1024] -> bf16 [rows][3072]: hi at 0 and hi2_off,
// ---- lo at lo_off.  A-style: lo_off=1024,hi2=2048. B-style: lo_off=2048,hi2=1024.
__global__ __launch_bounds__(256) void split3(const float* __restrict__ in,
                                              ushort* __restrict__ out3, int nrow,
                                              int lo_off, int hi2_off) {
    int idx = blockIdx.x * 256 + threadIdx.x;
    int row = idx >> 7, g = idx & 127;
    if (row >= nrow) return;
    const float* p = in + (size_t)row * 1024 + g * 8;
    float4 x0 = *(const float4*)p, x1 = *(const float4*)(p + 4);
    float xs[8] = {x0.x, x0.y, x0.z, x0.w, x1.x, x1.y, x1.z, x1.w};
    ushort hs[8], ls[8];
#pragma unroll
    for (int j = 0; j < 8; ++j) {
        ushort h = bf_rne(xs[j]);
        hs[j] = h;
        ls[j] = bf_rne(xs[j] - bf_to_f(h));
    }
    ushort* o = out3 + (size_t)row * 3072 + g * 8;
    ushort4 h0 = make_ushort4(hs[0], hs[1], hs[2], hs[3]);
    ushort4 h1 = make_ushort4(hs[4], hs[5], hs[6], hs[7]);
    *(ushort4*)(o)               = h0;
    *(ushort4*)(o + 4)           = h1;
    *(ushort4*)(o + hi2_off)     = h0;
    *(ushort4*)(o + hi2_off + 4) = h1;
    *(ushort4*)(o + lo_off)      = make_ushort4(ls[0], ls[1], ls[2], ls[3]);
    *(ushort4*)(o + lo_off + 4)  = make_ushort4(ls[4], ls[5], ls[6], ls[7]);
}

// -------- bf16 NT GEMM: C[M,1024] f32 = A3[M,3072] @ B3[1024,3072]^T --------
// 128x128 tile, BK=64, 4 waves (2x2, 64x64 each), dbuf LDS, gload_lds w=16.
__global__ __launch_bounds__(256) void gemm_bf16x3(const ushort* __restrict__ A3,
                                                   const ushort* __restrict__ B3,
                                                   float* __restrict__ Cm, int Nn) {
    __shared__ ushort As[2][8192];
    __shared__ ushort Bs[2][8192];
    const int tid = threadIdx.x;
    const int lane = tid & 63;
    const int wy = tid >> 7;
    const int wx = (tid >> 6) & 1;
    const int m0 = blockIdx.y * 128;
    const int n0 = blockIdx.x * 128;

    const int arow = tid >> 3;
    const int aslot = (tid & 7) ^ (arow & 7);
    const ushort* pA[4];
    const ushort* pB[4];
#pragma unroll
    for (int i = 0; i < 4; ++i) {
        pA[i] = A3 + (size_t)(m0 + i * 32 + arow) * K3 + aslot * 8;
        pB[i] = B3 + (size_t)(n0 + i * 32 + arow) * K3 + aslot * 8;
    }

#define STAGE(buf, kk)                                              \
    do {                                                            \
        _Pragma("unroll") for (int i = 0; i < 4; ++i)               \
            gload16(pA[i] + (kk), &As[buf][i * 2048 + tid * 8]);    \
        _Pragma("unroll") for (int i = 0; i < 4; ++i)               \
            gload16(pB[i] + (kk), &Bs[buf][i * 2048 + tid * 8]);    \
    } while (0)

    const int abase = (wy * 64 + (lane & 15)) * 64;
    const int bbase = (wx * 64 + (lane & 15)) * 64;

    floatx4 acc[4][4] = {};
    STAGE(0, 0);
    for (int t = 0; t < 48; ++t) {
        const int cur = t & 1;
        __syncthreads();
        if (t < 47) STAGE(1 - cur, (t + 1) * 64);
#pragma unroll
        for (int ksub = 0; ksub < 2; ++ksub) {
            const int so = ((((lane >> 4) | (ksub << 2)) ^ (lane & 7)) << 3);
            short8v a[4], b[4];
#pragma unroll
            for (int mf = 0; mf < 4; ++mf)
                a[mf] = *(const short8v*)&As[cur][abase + mf * 1024 + so];
#pragma unroll
            for (int nf = 0; nf < 4; ++nf)
                b[nf] = *(const short8v*)&Bs[cur][bbase + nf * 1024 + so];
#pragma unroll
            for (int mf = 0; mf < 4; ++mf)
#pragma unroll
                for (int nf = 0; nf < 4; ++nf)
                    acc[mf][nf] = __builtin_amdgcn_mfma_f32_16x16x32_bf16(
                        a[mf], b[nf], acc[mf][nf], 0, 0, 0);
        }
    }
#undef STAGE

#pragma unroll
    for (int mf = 0; mf < 4; ++mf) {
        int row = m0 + wy * 64 + mf * 16 + ((lane >> 4) << 2);
#pragma unroll
        for (int nf = 0; nf < 4; ++nf) {
            int col = n0 + wx * 64 + nf * 16 + (lane & 15);
#pragma unroll
            for (int r = 0; r < 4; ++r)
                Cm[(size_t)(row + r) * Nn + col] = acc[mf][nf][r];
        }
    }
}

// ---- fused q+k fp64-accumulate NT GEMM, SPLIT-K=2 (blockIdx.z) ----
// C f64 += X[4096, kh*512..+512] @ W^T slice. Tile 64x64, TK=32, float-
// staged LDS (stride 68), cvt+fp64 FMA in regs (R7-proven body).
// Grid (8,64,2) = 1024 blocks = 4 blocks/CU. Outputs pre-zeroed; epilogue
// f64 atomicAdd (2 commutative contributions per element).
__global__ __launch_bounds__(256) void gemm_qk_f64(const float* __restrict__ X,
                                                   const float* __restrict__ Wq,
                                                   const float* __restrict__ Wk,
                                                   double* __restrict__ q64,
                                                   double* __restrict__ k64) {
    __shared__ float As[TK][LDP];
    __shared__ float Bs[TK][LDP];
    const int tid = threadIdx.x;
    const int m0 = blockIdx.y * TM;
    const int n0g = blockIdx.x * TN;
    const int kh = blockIdx.z;            // K half: 0 or 1
    const bool isq = n0g < 256;
    const float* Wm = isq ? Wq : Wk;
    double* Cm = isq ? q64 : k64;
    const int n0 = isq ? n0g : n0g - 256;

    const int lr = tid >> 2;
    const int lc = (tid & 3) << 2;
    const int ty = tid >> 4;
    const int tx = tid & 15;

    double acc[4][4] = {};
    const float* Ap = X + (size_t)(m0 + lr) * 1024 + lc;
    const float* Bp = Wm + (size_t)(n0 + lr) * 1024 + lc;

    const int k0beg = kh * 512, k0end = k0beg + 512;
    for (int k0 = k0beg; k0 < k0end; k0 += TK) {
        float4 a0 = *(const float4*)(Ap + k0);
        float4 a1 = *(const float4*)(Ap + k0 + 16);
        float4 b0 = *(const float4*)(Bp + k0);
        float4 b1 = *(const float4*)(Bp + k0 + 16);
        __syncthreads();
        As[lc + 0][lr] = a0.x; As[lc + 1][lr] = a0.y;
        As[lc + 2][lr] = a0.z; As[lc + 3][lr] = a0.w;
        As[lc + 16][lr] = a1.x; As[lc + 17][lr] = a1.y;
        As[lc + 18][lr] = a1.z; As[lc + 19][lr] = a1.w;
        Bs[lc + 0][lr] = b0.x; Bs[lc + 1][lr] = b0.y;
        Bs[lc + 2][lr] = b0.z; Bs[lc + 3][lr] = b0.w;
        Bs[lc + 16][lr] = b1.x; Bs[lc + 17][lr] = b1.y;
        Bs[lc + 18][lr] = b1.z; Bs[lc + 19][lr] = b1.w;
        __syncthreads();
#pragma unroll
        for (int kk = 0; kk < TK; ++kk) {
            float4 av = *(const float4*)&As[kk][ty << 2];
            float4 bv = *(const float4*)&Bs[kk][tx << 2];
            double a[4] = {(double)av.x, (double)av.y, (double)av.z, (double)av.w};
            double b[4] = {(double)bv.x, (double)bv.y, (double)bv.z, (double)bv.w};
#pragma unroll
            for (int i = 0; i < 4; ++i)
#pragma unroll
                for (int j = 0; j < 4; ++j)
                    acc[i][j] += a[i] * b[j];
        }
    }
#pragma unroll
    for (int i = 0; i < 4; ++i) {
        size_t o = (size_t)(m0 + (ty << 2) + i) * 256 + n0 + (tx << 2);
#pragma unroll
        for (int j = 0; j < 4; ++j)
            atomicAdd(&Cm[o + j], acc[i][j]);
    }
}

// ------------- pass A: per-chunk KV fp32 (16x64) and Ksum fp64 (16) -------------
__global__ __launch_bounds__(256) void chunk_kv(const double* __restrict__ kg,
                                                const float* __restrict__ vg,
                                                float* __restrict__ KV,
                                                double* __restrict__ Ksum) {
    __shared__ double ksd[CHUNK][16];
    __shared__ float vs[CHUNK][64];
    const int c = blockIdx.x, bh = blockIdx.y;
    const int b = bh >> 4, h = bh & 15;
    const int n0 = b * L_ + c * CHUNK;
    const int tid = threadIdx.x;

    {
        int r = tid >> 1, o = (tid & 1) * 8;
        const double* kp = &kg[(size_t)(n0 + r) * 256 + h * 16 + o];
#pragma unroll
        for (int j = 0; j < 4; ++j)
            *(double2*)&ksd[r][o + j * 2] = *(const double2*)(kp + j * 2);
    }
    {
        int r = tid >> 1, half = (tid & 1) * 32;
        const float* vp = &vg[(size_t)(n0 + r) * 1024 + h * 64 + half];
#pragma unroll
        for (int j = 0; j < 8; ++j)
            *(float4*)&vs[r][half + j * 4] = *(const float4*)(vp + j * 4);
    }
    __syncthreads();

    const int f = tid >> 4;
    const int e4 = tid & 15;
    float a0 = 0.f, a1 = 0.f, a2 = 0.f, a3 = 0.f;
    double ksacc = 0.0;
    for (int l = 0; l < CHUNK; ++l) {
        double kd = ksd[l][f];
        float kv = (float)kd;
        float4 vv = *(const float4*)&vs[l][e4 << 2];
        a0 += kv * vv.x; a1 += kv * vv.y; a2 += kv * vv.z; a3 += kv * vv.w;
        ksacc += kd;
    }
    size_t o = ((size_t)bh * NCH + c) * 1024 + f * 64 + (e4 << 2);
    float4 r = {a0, a1, a2, a3};
    *(float4*)&KV[o] = r;
    if (e4 == 0) Ksum[((size_t)bh * NCH + c) * 16 + f] = ksacc;
}

// ------------- pass B: exclusive prefix over chunks -------------
__global__ __launch_bounds__(256) void prefix_kv(const float* __restrict__ KV,
                                                 const double* __restrict__ Ksum,
                                                 float* __restrict__ KVpre,
                                                 double* __restrict__ Kpre) {
    const int bh = blockIdx.x;
    const int t = threadIdx.x;
    float r0 = 0.f, r1 = 0.f, r2 = 0.f, r3 = 0.f;
    size_t base = (size_t)bh * NCH * 1024 + t * 4;
    for (int c = 0; c < NCH; ++c) {
        float4 w = {r0, r1, r2, r3};
        *(float4*)&KVpre[base + (size_t)c * 1024] = w;
        float4 cur = *(const float4*)&KV[base + (size_t)c * 1024];
        r0 += cur.x; r1 += cur.y; r2 += cur.z; r3 += cur.w;
    }
    if (t < 16) {
        double s = 0.0;
        size_t kb = (size_t)bh * NCH * 16 + t;
        for (int c = 0; c < NCH; ++c) {
            Kpre[kb + (size_t)c * 16] = s;
            s += Ksum[kb + (size_t)c * 16];
        }
    }
}

// ------------- pass C: per-chunk causal attention; writes y pre-split bf16x3 -------------
// Y3 written A-style [hi | lo | hi] (lo at +1024, hi copy at +2048).
__global__ __launch_bounds__(256) void attn_out(const double* __restrict__ qg,
                                                const double* __restrict__ kg,
                                                const float* __restrict__ vg,
                                                const float* __restrict__ kvpre,
                                                const double* __restrict__ kpreg,
                                                ushort* __restrict__ y3) {
    __shared__ double qs[CHUNK][16];
    __shared__ double ks[CHUNK][16];
    __shared__ float vs[CHUNK][64];
    __shared__ float s0[16][64];
    __shared__ double kp[16];
    const int c = blockIdx.x, bh = blockIdx.y;
    const int b = bh >> 4, h = bh & 15;
    const int n0 = b * L_ + c * CHUNK;
    const int tid = threadIdx.x;

    {
        int r = tid >> 1, o = (tid & 1) * 8;
        const double* qp = &qg[(size_t)(n0 + r) * 256 + h * 16 + o];
        const double* kptr = &kg[(size_t)(n0 + r) * 256 + h * 16 + o];
#pragma unroll
        for (int j = 0; j < 4; ++j) {
            *(double2*)&qs[r][o + j * 2] = *(const double2*)(qp + j * 2);
            *(double2*)&ks[r][o + j * 2] = *(const double2*)(kptr + j * 2);
        }
    }
    {
        int r = tid >> 1, half = (tid & 1) * 32;
        const float* vp = &vg[(size_t)(n0 + r) * 1024 + h * 64 + half];
#pragma unroll
        for (int j = 0; j < 8; ++j)
            *(float4*)&vs[r][half + j * 4] = *(const float4*)(vp + j * 4);
    }
    {
        float4 w = *(const float4*)&kvpre[((size_t)bh * NCH + c) * 1024 + tid * 4];
        *(float4*)&s0[0][tid * 4] = w;
        if (tid < 16) kp[tid] = kpreg[((size_t)bh * NCH + c) * 16 + tid];
    }
    __syncthreads();

    const int i = tid >> 1;
    const int half = (tid & 1) * 32;

    double qr[16];
#pragma unroll
    for (int f = 0; f < 16; ++f) qr[f] = qs[i][f];

    double denom = 0.0;
#pragma unroll
    for (int f = 0; f < 16; ++f) denom += qr[f] * kp[f];

    float acc[32] = {};
#pragma unroll
    for (int f = 0; f < 16; ++f) {
        float qf = (float)qr[f];
#pragma unroll
        for (int e = 0; e < 32; e += 4) {
            float4 sv = *(const float4*)&s0[f][half + e];
            acc[e + 0] += qf * sv.x; acc[e + 1] += qf * sv.y;
            acc[e + 2] += qf * sv.z; acc[e + 3] += qf * sv.w;
        }
    }
    for (int j = 0; j <= i; ++j) {
        double s64 = 0.0;
#pragma unroll
        for (int f = 0; f < 16; ++f) s64 += qr[f] * ks[j][f];
        denom += s64;
        float s = (float)s64;
        const float4* vj = (const float4*)&vs[j][half];
#pragma unroll
        for (int e4 = 0; e4 < 8; ++e4) {
            float4 vv = vj[e4];
            acc[e4 * 4 + 0] += s * vv.x; acc[e4 * 4 + 1] += s * vv.y;
            acc[e4 * 4 + 2] += s * vv.z; acc[e4 * 4 + 3] += s * vv.w;
        }
    }

    const float z = (float)(1.0 / (denom + 1e-12));
    ushort* yp = &y3[(size_t)(n0 + i) * K3 + h * 64 + half];
#pragma unroll
    for (int e4 = 0; e4 < 8; ++e4) {
        ushort hs[4], ls[4];
#pragma unroll
        for (int j = 0; j < 4; ++j) {
            float val = acc[e4 * 4 + j] * z;
            ushort hh = bf_rne(val);
            hs[j] = hh;
            ls[j] = bf_rne(val - bf_to_f(hh));
        }
        ushort4 hv = make_ushort4(hs[0], hs[1], hs[2], hs[3]);
        *(ushort4*)(yp + e4 * 4)        = hv;   // hi
        *(ushort4*)(yp + 1024 + e4 * 4) = make_ushort4(ls[0], ls[1], ls[2], ls[3]); // lo
        *(ushort4*)(yp + 2048 + e4 * 4) = hv;   // hi copy
    }
}

extern "C" void kernel_launch(void* const* d_in, const int* in_sizes, int n_in,
                              void* d_out, int out_size, void* d_ws, size_t ws_size,
                              hipStream_t stream) {
    const float* X  = (const float*)d_in[0];
    const float* Wq = (const float*)d_in[1];
    const float* Wk = (const float*)d_in[2];
    const float* Wv = (const float*)d_in[3];
    const float* Wo = (const float*)d_in[4];
    float* out = (float*)d_out;

    double* q64   = (double*)d_ws;                 // 8 MB
    double* k64   = q64 + 1048576;                 // 8 MB
    float*  v     = (float*)(k64 + 1048576);       // 16 MB
    float*  KV    = v + 4194304;                   // 2 MB
    float*  KVpre = KV + 524288;                   // 2 MB
    double* Ksum  = (double*)(KVpre + 524288);     // 64 KB
    double* Kpre  = Ksum + 8192;                   // 64 KB
    ushort* X3    = (ushort*)(Kpre + 8192);        // 24 MB (reused as Y3)
    ushort* Wv3   = X3 + (size_t)4096 * K3;        // 6 MB
    ushort* Wo3   = Wv3 + (size_t)1024 * K3;       // 6 MB
    // total ~72.2 MB

    dim3 blk(256);
    // zero q64,k64 (16 MB contiguous) for split-K atomic accumulation
    hipMemsetAsync(q64, 0, (size_t)2097152 * sizeof(double), stream);
    split3<<<2048, blk, 0, stream>>>(X, X3, 4096, 1024, 2048);   // A-style [hi|lo|hi]
    split3<<<512, blk, 0, stream>>>(Wv, Wv3, 1024, 2048, 1024);  // B-style [hi|hi|lo]
    split3<<<512, blk, 0, stream>>>(Wo, Wo3, 1024, 2048, 1024);  // B-style [hi|hi|lo]
    gemm_qk_f64<<<dim3(8, 64, 2), blk, 0, stream>>>(X, Wq, Wk, q64, k64);
    gemm_bf16x3<<<dim3(8, 32), blk, 0, stream>>>(X3, Wv3, v, 1024);
    chunk_kv<<<dim3(NCH, NBH), blk, 0, stream>>>(k64, v, KV, Ksum);
    prefix_kv<<<dim3(NBH), blk, 0, stream>>>(KV, Ksum, KVpre, Kpre);
    attn_out<<<dim3(NCH, NBH), blk, 0, stream>>>(q64, k64, v, KVpre, Kpre, X3);
    gemm_bf16x3<<<dim3(8, 32), blk, 0, stream>>>(X3, Wo3, out, 1024);
}

// Round 10
// 303.111 us; speedup vs baseline: 1.2697x; 1.2697x over previous
//
#include <hip/hip_runtime.h>

// LinearAttention: B=2, L=2048, D=1024, H=16, FD=16, HD=64. fp32 in/out.
// Denominator chain (q,k proj + cumsum + dots) stays fp64 (cancellation,
// z amplifies ~3e4). v-proj/out-proj: bf16x3-split MFMA GEMMs
// (A3=[Ahi|Alo|Ahi], B3=[Bhi|Bhi|Blo] => Ahi.Bhi+Alo.Bhi+Ahi.Blo).
// q,k proj: R7-proven fused vector-fp64 GEMM 64x64/TK=32, grid 512
// (2 blocks/CU — R9 showed scaling saturates there; atomics/split-K REGRESS:
// +115 MB RMW traffic). bf16x3 GEMMs retiled 128x128->128x64: 1 -> 3
// blocks/CU (48KB LDS), same arithmetic order (bit-identical output).
// R8 lesson: never fuse divergent bodies (union regalloc kills occupancy).

#define L_    2048
#define NROW  4096   // B*L
#define CHUNK 128
#define NCH   16
#define NBH   32
#define K3    3072

#define TM 64
#define TN 64
#define TK 32
#define LDP 68

typedef __attribute__((ext_vector_type(8))) short short8v;
typedef __attribute__((ext_vector_type(4))) float floatx4;

__device__ __forceinline__ ushort bf_rne(float x) {
    unsigned u = __float_as_uint(x);
    return (ushort)((u + 0x7fffu + ((u >> 16) & 1u)) >> 16);
}
__device__ __forceinline__ float bf_to_f(ushort h) {
    return __uint_as_float(((unsigned)h) << 16);
}
__device__ __forceinline__ void gload16(const ushort* g, ushort* l) {
    __builtin_amdgcn_global_load_lds(
        (const __attribute__((address_space(1))) unsigned int*)g,
        (__attribute__((address_space(3))) unsigned int*)l, 16, 0, 0);
}

// ---- split fp32 [rows][1024] -> bf16 [rows][3072]: hi at 0 and hi2_off,
// ---- lo at lo_off.  A-style: lo_off=1024,hi2=2048. B-style: lo_off=2048,hi2=1024.
__global__ __launch_bounds__(256) void split3(const float* __restrict__ in,
                                              ushort* __restrict__ out3, int nrow,
                                              int lo_off, int hi2_off) {
    int idx = blockIdx.x * 256 + threadIdx.x;
    int row = idx >> 7, g = idx & 127;
    if (row >= nrow) return;
    const float* p = in + (size_t)row * 1024 + g * 8;
    float4 x0 = *(const float4*)p, x1 = *(const float4*)(p + 4);
    float xs[8] = {x0.x, x0.y, x0.z, x0.w, x1.x, x1.y, x1.z, x1.w};
    ushort hs[8], ls[8];
#pragma unroll
    for (int j = 0; j < 8; ++j) {
        ushort h = bf_rne(xs[j]);
        hs[j] = h;
        ls[j] = bf_rne(xs[j] - bf_to_f(h));
    }
    ushort* o = out3 + (size_t)row * 3072 + g * 8;
    ushort4 h0 = make_ushort4(hs[0], hs[1], hs[2], hs[3]);
    ushort4 h1 = make_ushort4(hs[4], hs[5], hs[6], hs[7]);
    *(ushort4*)(o)               = h0;
    *(ushort4*)(o + 4)           = h1;
    *(ushort4*)(o + hi2_off)     = h0;
    *(ushort4*)(o + hi2_off + 4) = h1;
    *(ushort4*)(o + lo_off)      = make_ushort4(ls[0], ls[1], ls[2], ls[3]);
    *(ushort4*)(o + lo_off + 4)  = make_ushort4(ls[4], ls[5], ls[6], ls[7]);
}

// -------- bf16 NT GEMM: C[M,1024] f32 = A3[M,3072] @ B3[1024,3072]^T --------
// Tile 128(M)x64(N), BK=64, 4 waves 2x2 (wave = 64x32), dbuf LDS 48KB ->
// 3 blocks/CU, gload_lds w=16, grid (16,32) = 512 blocks.
__global__ __launch_bounds__(256) void gemm_bf16x3(const ushort* __restrict__ A3,
                                                   const ushort* __restrict__ B3,
                                                   float* __restrict__ Cm, int Nn) {
    __shared__ ushort As[2][8192];
    __shared__ ushort Bs[2][4096];
    const int tid = threadIdx.x;
    const int lane = tid & 63;
    const int wy = tid >> 7;
    const int wx = (tid >> 6) & 1;
    const int m0 = blockIdx.y * 128;
    const int n0 = blockIdx.x * 64;

    const int arow = tid >> 3;                   // 0..31
    const int aslot = (tid & 7) ^ (arow & 7);    // inverse-swizzled source slot
    const ushort* pA[4];
    const ushort* pB[2];
#pragma unroll
    for (int i = 0; i < 4; ++i)
        pA[i] = A3 + (size_t)(m0 + i * 32 + arow) * K3 + aslot * 8;
#pragma unroll
    for (int i = 0; i < 2; ++i)
        pB[i] = B3 + (size_t)(n0 + i * 32 + arow) * K3 + aslot * 8;

#define STAGE(buf, kk)                                              \
    do {                                                            \
        _Pragma("unroll") for (int i = 0; i < 4; ++i)               \
            gload16(pA[i] + (kk), &As[buf][i * 2048 + tid * 8]);    \
        _Pragma("unroll") for (int i = 0; i < 2; ++i)               \
            gload16(pB[i] + (kk), &Bs[buf][i * 2048 + tid * 8]);    \
    } while (0)

    const int abase = (wy * 64 + (lane & 15)) * 64;
    const int bbase = (wx * 32 + (lane & 15)) * 64;

    floatx4 acc[4][2] = {};
    STAGE(0, 0);
    for (int t = 0; t < 48; ++t) {
        const int cur = t & 1;
        __syncthreads();
        if (t < 47) STAGE(1 - cur, (t + 1) * 64);
#pragma unroll
        for (int ksub = 0; ksub < 2; ++ksub) {
            const int so = ((((lane >> 4) | (ksub << 2)) ^ (lane & 7)) << 3);
            short8v a[4], b[2];
#pragma unroll
            for (int mf = 0; mf < 4; ++mf)
                a[mf] = *(const short8v*)&As[cur][abase + mf * 1024 + so];
#pragma unroll
            for (int nf = 0; nf < 2; ++nf)
                b[nf] = *(const short8v*)&Bs[cur][bbase + nf * 1024 + so];
#pragma unroll
            for (int mf = 0; mf < 4; ++mf)
#pragma unroll
                for (int nf = 0; nf < 2; ++nf)
                    acc[mf][nf] = __builtin_amdgcn_mfma_f32_16x16x32_bf16(
                        a[mf], b[nf], acc[mf][nf], 0, 0, 0);
        }
    }
#undef STAGE

#pragma unroll
    for (int mf = 0; mf < 4; ++mf) {
        int row = m0 + wy * 64 + mf * 16 + ((lane >> 4) << 2);
#pragma unroll
        for (int nf = 0; nf < 2; ++nf) {
            int col = n0 + wx * 32 + nf * 16 + (lane & 15);
#pragma unroll
            for (int r = 0; r < 4; ++r)
                Cm[(size_t)(row + r) * Nn + col] = acc[mf][nf][r];
        }
    }
}

// ---- fused q+k fp64-accumulate NT GEMM (R7-proven, unchanged) ----
// C f64 = X[4096,1024] @ W^T, W = Wq (n0g<256) else Wk. Tile 64x64, TK=32,
// float-staged LDS (stride 68), cvt+fp64 FMA in regs. Grid (8,64) = 512.
__global__ __launch_bounds__(256) void gemm_qk_f64(const float* __restrict__ X,
                                                   const float* __restrict__ Wq,
                                                   const float* __restrict__ Wk,
                                                   double* __restrict__ q64,
                                                   double* __restrict__ k64) {
    __shared__ float As[TK][LDP];
    __shared__ float Bs[TK][LDP];
    const int tid = threadIdx.x;
    const int m0 = blockIdx.y * TM;
    const int n0g = blockIdx.x * TN;
    const bool isq = n0g < 256;
    const float* Wm = isq ? Wq : Wk;
    double* Cm = isq ? q64 : k64;
    const int n0 = isq ? n0g : n0g - 256;

    const int lr = tid >> 2;
    const int lc = (tid & 3) << 2;
    const int ty = tid >> 4;
    const int tx = tid & 15;

    double acc[4][4] = {};
    const float* Ap = X + (size_t)(m0 + lr) * 1024 + lc;
    const float* Bp = Wm + (size_t)(n0 + lr) * 1024 + lc;

    for (int k0 = 0; k0 < 1024; k0 += TK) {
        float4 a0 = *(const float4*)(Ap + k0);
        float4 a1 = *(const float4*)(Ap + k0 + 16);
        float4 b0 = *(const float4*)(Bp + k0);
        float4 b1 = *(const float4*)(Bp + k0 + 16);
        __syncthreads();
        As[lc + 0][lr] = a0.x; As[lc + 1][lr] = a0.y;
        As[lc + 2][lr] = a0.z; As[lc + 3][lr] = a0.w;
        As[lc + 16][lr] = a1.x; As[lc + 17][lr] = a1.y;
        As[lc + 18][lr] = a1.z; As[lc + 19][lr] = a1.w;
        Bs[lc + 0][lr] = b0.x; Bs[lc + 1][lr] = b0.y;
        Bs[lc + 2][lr] = b0.z; Bs[lc + 3][lr] = b0.w;
        Bs[lc + 16][lr] = b1.x; Bs[lc + 17][lr] = b1.y;
        Bs[lc + 18][lr] = b1.z; Bs[lc + 19][lr] = b1.w;
        __syncthreads();
#pragma unroll
        for (int kk = 0; kk < TK; ++kk) {
            float4 av = *(const float4*)&As[kk][ty << 2];
            float4 bv = *(const float4*)&Bs[kk][tx << 2];
            double a[4] = {(double)av.x, (double)av.y, (double)av.z, (double)av.w};
            double b[4] = {(double)bv.x, (double)bv.y, (double)bv.z, (double)bv.w};
#pragma unroll
            for (int i = 0; i < 4; ++i)
#pragma unroll
                for (int j = 0; j < 4; ++j)
                    acc[i][j] += a[i] * b[j];
        }
    }
#pragma unroll
    for (int i = 0; i < 4; ++i) {
        size_t o = (size_t)(m0 + (ty << 2) + i) * 256 + n0 + (tx << 2);
        double2 r0 = {acc[i][0], acc[i][1]};
        double2 r1 = {acc[i][2], acc[i][3]};
        *(double2*)&Cm[o] = r0;
        *(double2*)&Cm[o + 2] = r1;
    }
}

// ------------- pass A: per-chunk KV fp32 (16x64) and Ksum fp64 (16) -------------
__global__ __launch_bounds__(256) void chunk_kv(const double* __restrict__ kg,
                                                const float* __restrict__ vg,
                                                float* __restrict__ KV,
                                                double* __restrict__ Ksum) {
    __shared__ double ksd[CHUNK][16];
    __shared__ float vs[CHUNK][64];
    const int c = blockIdx.x, bh = blockIdx.y;
    const int b = bh >> 4, h = bh & 15;
    const int n0 = b * L_ + c * CHUNK;
    const int tid = threadIdx.x;

    {
        int r = tid >> 1, o = (tid & 1) * 8;
        const double* kp = &kg[(size_t)(n0 + r) * 256 + h * 16 + o];
#pragma unroll
        for (int j = 0; j < 4; ++j)
            *(double2*)&ksd[r][o + j * 2] = *(const double2*)(kp + j * 2);
    }
    {
        int r = tid >> 1, half = (tid & 1) * 32;
        const float* vp = &vg[(size_t)(n0 + r) * 1024 + h * 64 + half];
#pragma unroll
        for (int j = 0; j < 8; ++j)
            *(float4*)&vs[r][half + j * 4] = *(const float4*)(vp + j * 4);
    }
    __syncthreads();

    const int f = tid >> 4;
    const int e4 = tid & 15;
    float a0 = 0.f, a1 = 0.f, a2 = 0.f, a3 = 0.f;
    double ksacc = 0.0;
    for (int l = 0; l < CHUNK; ++l) {
        double kd = ksd[l][f];
        float kv = (float)kd;
        float4 vv = *(const float4*)&vs[l][e4 << 2];
        a0 += kv * vv.x; a1 += kv * vv.y; a2 += kv * vv.z; a3 += kv * vv.w;
        ksacc += kd;
    }
    size_t o = ((size_t)bh * NCH + c) * 1024 + f * 64 + (e4 << 2);
    float4 r = {a0, a1, a2, a3};
    *(float4*)&KV[o] = r;
    if (e4 == 0) Ksum[((size_t)bh * NCH + c) * 16 + f] = ksacc;
}

// ------------- pass B: exclusive prefix over chunks -------------
__global__ __launch_bounds__(256) void prefix_kv(const float* __restrict__ KV,
                                                 const double* __restrict__ Ksum,
                                                 float* __restrict__ KVpre,
                                                 double* __restrict__ Kpre) {
    const int bh = blockIdx.x;
    const int t = threadIdx.x;
    float r0 = 0.f, r1 = 0.f, r2 = 0.f, r3 = 0.f;
    size_t base = (size_t)bh * NCH * 1024 + t * 4;
    for (int c = 0; c < NCH; ++c) {
        float4 w = {r0, r1, r2, r3};
        *(float4*)&KVpre[base + (size_t)c * 1024] = w;
        float4 cur = *(const float4*)&KV[base + (size_t)c * 1024];
        r0 += cur.x; r1 += cur.y; r2 += cur.z; r3 += cur.w;
    }
    if (t < 16) {
        double s = 0.0;
        size_t kb = (size_t)bh * NCH * 16 + t;
        for (int c = 0; c < NCH; ++c) {
            Kpre[kb + (size_t)c * 16] = s;
            s += Ksum[kb + (size_t)c * 16];
        }
    }
}

// ------------- pass C: per-chunk causal attention; writes y pre-split bf16x3 -------------
// Y3 written A-style [hi | lo | hi] (lo at +1024, hi copy at +2048).
__global__ __launch_bounds__(256) void attn_out(const double* __restrict__ qg,
                                                const double* __restrict__ kg,
                                                const float* __restrict__ vg,
                                                const float* __restrict__ kvpre,
                                                const double* __restrict__ kpreg,
                                                ushort* __restrict__ y3) {
    __shared__ double qs[CHUNK][16];
    __shared__ double ks[CHUNK][16];
    __shared__ float vs[CHUNK][64];
    __shared__ float s0[16][64];
    __shared__ double kp[16];
    const int c = blockIdx.x, bh = blockIdx.y;
    const int b = bh >> 4, h = bh & 15;
    const int n0 = b * L_ + c * CHUNK;
    const int tid = threadIdx.x;

    {
        int r = tid >> 1, o = (tid & 1) * 8;
        const double* qp = &qg[(size_t)(n0 + r) * 256 + h * 16 + o];
        const double* kptr = &kg[(size_t)(n0 + r) * 256 + h * 16 + o];
#pragma unroll
        for (int j = 0; j < 4; ++j) {
            *(double2*)&qs[r][o + j * 2] = *(const double2*)(qp + j * 2);
            *(double2*)&ks[r][o + j * 2] = *(const double2*)(kptr + j * 2);
        }
    }
    {
        int r = tid >> 1, half = (tid & 1) * 32;
        const float* vp = &vg[(size_t)(n0 + r) * 1024 + h * 64 + half];
#pragma unroll
        for (int j = 0; j < 8; ++j)
            *(float4*)&vs[r][half + j * 4] = *(const float4*)(vp + j * 4);
    }
    {
        float4 w = *(const float4*)&kvpre[((size_t)bh * NCH + c) * 1024 + tid * 4];
        *(float4*)&s0[0][tid * 4] = w;
        if (tid < 16) kp[tid] = kpreg[((size_t)bh * NCH + c) * 16 + tid];
    }
    __syncthreads();

    const int i = tid >> 1;
    const int half = (tid & 1) * 32;

    double qr[16];
#pragma unroll
    for (int f = 0; f < 16; ++f) qr[f] = qs[i][f];

    double denom = 0.0;
#pragma unroll
    for (int f = 0; f < 16; ++f) denom += qr[f] * kp[f];

    float acc[32] = {};
#pragma unroll
    for (int f = 0; f < 16; ++f) {
        float qf = (float)qr[f];
#pragma unroll
        for (int e = 0; e < 32; e += 4) {
            float4 sv = *(const float4*)&s0[f][half + e];
            acc[e + 0] += qf * sv.x; acc[e + 1] += qf * sv.y;
            acc[e + 2] += qf * sv.z; acc[e + 3] += qf * sv.w;
        }
    }
    for (int j = 0; j <= i; ++j) {
        double s64 = 0.0;
#pragma unroll
        for (int f = 0; f < 16; ++f) s64 += qr[f] * ks[j][f];
        denom += s64;
        float s = (float)s64;
        const float4* vj = (const float4*)&vs[j][half];
#pragma unroll
        for (int e4 = 0; e4 < 8; ++e4) {
            float4 vv = vj[e4];
            acc[e4 * 4 + 0] += s * vv.x; acc[e4 * 4 + 1] += s * vv.y;
            acc[e4 * 4 + 2] += s * vv.z; acc[e4 * 4 + 3] += s * vv.w;
        }
    }

    const float z = (float)(1.0 / (denom + 1e-12));
    ushort* yp = &y3[(size_t)(n0 + i) * K3 + h * 64 + half];
#pragma unroll
    for (int e4 = 0; e4 < 8; ++e4) {
        ushort hs[4], ls[4];
#pragma unroll
        for (int j = 0; j < 4; ++j) {
            float val = acc[e4 * 4 + j] * z;
            ushort hh = bf_rne(val);
            hs[j] = hh;
            ls[j] = bf_rne(val - bf_to_f(hh));
        }
        ushort4 hv = make_ushort4(hs[0], hs[1], hs[2], hs[3]);
        *(ushort4*)(yp + e4 * 4)        = hv;   // hi
        *(ushort4*)(yp + 1024 + e4 * 4) = make_ushort4(ls[0], ls[1], ls[2], ls[3]); // lo
        *(ushort4*)(yp + 2048 + e4 * 4) = hv;   // hi copy
    }
}

extern "C" void kernel_launch(void* const* d_in, const int* in_sizes, int n_in,
                              void* d_out, int out_size, void* d_ws, size_t ws_size,
                              hipStream_t stream) {
    const float* X  = (const float*)d_in[0];
    const float* Wq = (const float*)d_in[1];
    const float* Wk = (const float*)d_in[2];
    const float* Wv = (const float*)d_in[3];
    const float* Wo = (const float*)d_in[4];
    float* out = (float*)d_out;

    double* q64   = (double*)d_ws;                 // 8 MB
    double* k64   = q64 + 1048576;                 // 8 MB
    float*  v     = (float*)(k64 + 1048576);       // 16 MB
    float*  KV    = v + 4194304;                   // 2 MB
    float*  KVpre = KV + 524288;                   // 2 MB
    double* Ksum  = (double*)(KVpre + 524288);     // 64 KB
    double* Kpre  = Ksum + 8192;                   // 64 KB
    ushort* X3    = (ushort*)(Kpre + 8192);        // 24 MB (reused as Y3)
    ushort* Wv3   = X3 + (size_t)4096 * K3;        // 6 MB
    ushort* Wo3   = Wv3 + (size_t)1024 * K3;       // 6 MB
    // total ~72.2 MB

    dim3 blk(256);
    split3<<<2048, blk, 0, stream>>>(X, X3, 4096, 1024, 2048);   // A-style [hi|lo|hi]
    split3<<<512, blk, 0, stream>>>(Wv, Wv3, 1024, 2048, 1024);  // B-style [hi|hi|lo]
    split3<<<512, blk, 0, stream>>>(Wo, Wo3, 1024, 2048, 1024);  // B-style [hi|hi|lo]
    gemm_qk_f64<<<dim3(8, 64), blk, 0, stream>>>(X, Wq, Wk, q64, k64);
    gemm_bf16x3<<<dim3(16, 32), blk, 0, stream>>>(X3, Wv3, v, 1024);
    chunk_kv<<<dim3(NCH, NBH), blk, 0, stream>>>(k64, v, KV, Ksum);
    prefix_kv<<<dim3(NBH), blk, 0, stream>>>(KV, Ksum, KVpre, Kpre);
    attn_out<<<dim3(NCH, NBH), blk, 0, stream>>>(q64, k64, v, KVpre, Kpre, X3);
    gemm_bf16x3<<<dim3(16, 32), blk, 0, stream>>>(X3, Wo3, out, 1024);
}

// Round 11
// 301.950 us; speedup vs baseline: 1.2746x; 1.0038x over previous
//
#include <hip/hip_runtime.h>

// LinearAttention: B=2, L=2048, D=1024, H=16, FD=16, HD=64. fp32 in/out.
// Denominator chain (q,k proj + cumsum + dots) stays fp64 (cancellation,
// z amplifies ~3e4; bf16-split q/k ruled out analytically: hi+lo rep error
// 2^-18 -> ~30% denom error at amplified points). v-proj/out-proj: bf16x3
// MFMA GEMMs (A3=[Ahi|Alo|Ahi], B3=[Bhi|Bhi|Blo]).
// q,k proj: fused vector-fp64 GEMM 64x64, now TK=16 with F64-STAGED LDS —
// R10 showed fp64 is half-rate (~39 T FMA/s) and the 8 cvt/16 FMA inner mix
// plus f32 LDS reads were 20% of VALU cycles; converting at staging makes
// the inner loop pure v_fma_f64. Bit-identical output to R10.
// Lessons: no divergent-body fusion (R8); no split-K atomics (R9); 2
// blocks/CU suffices for this loop (R9).

#define L_    2048
#define NROW  4096   // B*L
#define CHUNK 128
#define NCH   16
#define NBH   32
#define K3    3072

#define TM 64
#define TN 64

typedef __attribute__((ext_vector_type(8))) short short8v;
typedef __attribute__((ext_vector_type(4))) float floatx4;

__device__ __forceinline__ ushort bf_rne(float x) {
    unsigned u = __float_as_uint(x);
    return (ushort)((u + 0x7fffu + ((u >> 16) & 1u)) >> 16);
}
__device__ __forceinline__ float bf_to_f(ushort h) {
    return __uint_as_float(((unsigned)h) << 16);
}
__device__ __forceinline__ void gload16(const ushort* g, ushort* l) {
    __builtin_amdgcn_global_load_lds(
        (const __attribute__((address_space(1))) unsigned int*)g,
        (__attribute__((address_space(3))) unsigned int*)l, 16, 0, 0);
}

// ---- split fp32 [rows][1024] -> bf16 [rows][3072]: hi at 0 and hi2_off,
// ---- lo at lo_off.  A-style: lo_off=1024,hi2=2048. B-style: lo_off=2048,hi2=1024.
__global__ __launch_bounds__(256) void split3(const float* __restrict__ in,
                                              ushort* __restrict__ out3, int nrow,
                                              int lo_off, int hi2_off) {
    int idx = blockIdx.x * 256 + threadIdx.x;
    int row = idx >> 7, g = idx & 127;
    if (row >= nrow) return;
    const float* p = in + (size_t)row * 1024 + g * 8;
    float4 x0 = *(const float4*)p, x1 = *(const float4*)(p + 4);
    float xs[8] = {x0.x, x0.y, x0.z, x0.w, x1.x, x1.y, x1.z, x1.w};
    ushort hs[8], ls[8];
#pragma unroll
    for (int j = 0; j < 8; ++j) {
        ushort h = bf_rne(xs[j]);
        hs[j] = h;
        ls[j] = bf_rne(xs[j] - bf_to_f(h));
    }
    ushort* o = out3 + (size_t)row * 3072 + g * 8;
    ushort4 h0 = make_ushort4(hs[0], hs[1], hs[2], hs[3]);
    ushort4 h1 = make_ushort4(hs[4], hs[5], hs[6], hs[7]);
    *(ushort4*)(o)               = h0;
    *(ushort4*)(o + 4)           = h1;
    *(ushort4*)(o + hi2_off)     = h0;
    *(ushort4*)(o + hi2_off + 4) = h1;
    *(ushort4*)(o + lo_off)      = make_ushort4(ls[0], ls[1], ls[2], ls[3]);
    *(ushort4*)(o + lo_off + 4)  = make_ushort4(ls[4], ls[5], ls[6], ls[7]);
}

// -------- bf16 NT GEMM: C[M,1024] f32 = A3[M,3072] @ B3[1024,3072]^T --------
// Tile 128(M)x64(N), BK=64, 4 waves 2x2 (wave = 64x32), dbuf LDS 48KB ->
// 3 blocks/CU, gload_lds w=16, grid (16,32) = 512 blocks. (R10-proven)
__global__ __launch_bounds__(256) void gemm_bf16x3(const ushort* __restrict__ A3,
                                                   const ushort* __restrict__ B3,
                                                   float* __restrict__ Cm, int Nn) {
    __shared__ ushort As[2][8192];
    __shared__ ushort Bs[2][4096];
    const int tid = threadIdx.x;
    const int lane = tid & 63;
    const int wy = tid >> 7;
    const int wx = (tid >> 6) & 1;
    const int m0 = blockIdx.y * 128;
    const int n0 = blockIdx.x * 64;

    const int arow = tid >> 3;                   // 0..31
    const int aslot = (tid & 7) ^ (arow & 7);    // inverse-swizzled source slot
    const ushort* pA[4];
    const ushort* pB[2];
#pragma unroll
    for (int i = 0; i < 4; ++i)
        pA[i] = A3 + (size_t)(m0 + i * 32 + arow) * K3 + aslot * 8;
#pragma unroll
    for (int i = 0; i < 2; ++i)
        pB[i] = B3 + (size_t)(n0 + i * 32 + arow) * K3 + aslot * 8;

#define STAGE(buf, kk)                                              \
    do {                                                            \
        _Pragma("unroll") for (int i = 0; i < 4; ++i)               \
            gload16(pA[i] + (kk), &As[buf][i * 2048 + tid * 8]);    \
        _Pragma("unroll") for (int i = 0; i < 2; ++i)               \
            gload16(pB[i] + (kk), &Bs[buf][i * 2048 + tid * 8]);    \
    } while (0)

    const int abase = (wy * 64 + (lane & 15)) * 64;
    const int bbase = (wx * 32 + (lane & 15)) * 64;

    floatx4 acc[4][2] = {};
    STAGE(0, 0);
    for (int t = 0; t < 48; ++t) {
        const int cur = t & 1;
        __syncthreads();
        if (t < 47) STAGE(1 - cur, (t + 1) * 64);
#pragma unroll
        for (int ksub = 0; ksub < 2; ++ksub) {
            const int so = ((((lane >> 4) | (ksub << 2)) ^ (lane & 7)) << 3);
            short8v a[4], b[2];
#pragma unroll
            for (int mf = 0; mf < 4; ++mf)
                a[mf] = *(const short8v*)&As[cur][abase + mf * 1024 + so];
#pragma unroll
            for (int nf = 0; nf < 2; ++nf)
                b[nf] = *(const short8v*)&Bs[cur][bbase + nf * 1024 + so];
#pragma unroll
            for (int mf = 0; mf < 4; ++mf)
#pragma unroll
                for (int nf = 0; nf < 2; ++nf)
                    acc[mf][nf] = __builtin_amdgcn_mfma_f32_16x16x32_bf16(
                        a[mf], b[nf], acc[mf][nf], 0, 0, 0);
        }
    }
#undef STAGE

#pragma unroll
    for (int mf = 0; mf < 4; ++mf) {
        int row = m0 + wy * 64 + mf * 16 + ((lane >> 4) << 2);
#pragma unroll
        for (int nf = 0; nf < 2; ++nf) {
            int col = n0 + wx * 32 + nf * 16 + (lane & 15);
#pragma unroll
            for (int r = 0; r < 4; ++r)
                Cm[(size_t)(row + r) * Nn + col] = acc[mf][nf][r];
        }
    }
}

// ---- fused q+k fp64 NT GEMM, TK=16, f64-staged LDS ----
// C f64 = X[4096,1024] @ W^T, W = Wq (n0g<256) else Wk. Tile 64x64.
// f32->f64 convert at staging (8 cvt/thread/tile); inner loop pure
// v_fma_f64 + ds_read_b128. Stride 66 dbl: rows 528B (16B-aligned b128),
// A-reads broadcast over tx. Same lane->elem map as R10 => bit-identical.
// Grid (8,64) = 512 blocks = 2 blocks/CU.
__global__ __launch_bounds__(256) void gemm_qk_f64(const float* __restrict__ X,
                                                   const float* __restrict__ Wq,
                                                   const float* __restrict__ Wk,
                                                   double* __restrict__ q64,
                                                   double* __restrict__ k64) {
    __shared__ __align__(16) double As[16][66];
    __shared__ __align__(16) double Bs[16][66];
    const int tid = threadIdx.x;
    const int m0 = blockIdx.y * TM;
    const int n0g = blockIdx.x * TN;
    const bool isq = n0g < 256;
    const float* Wm = isq ? Wq : Wk;
    double* Cm = isq ? q64 : k64;
    const int n0 = isq ? n0g : n0g - 256;

    const int lr = tid >> 2;          // 0..63 row
    const int lc = (tid & 3) << 2;    // kk offset 0,4,8,12
    const int ty = tid >> 4;
    const int tx = tid & 15;

    double acc[4][4] = {};
    const float* Ap = X + (size_t)(m0 + lr) * 1024 + lc;
    const float* Bp = Wm + (size_t)(n0 + lr) * 1024 + lc;

    for (int k0 = 0; k0 < 1024; k0 += 16) {
        float4 a0 = *(const float4*)(Ap + k0);
        float4 b0 = *(const float4*)(Bp + k0);
        __syncthreads();
        As[lc + 0][lr] = (double)a0.x; As[lc + 1][lr] = (double)a0.y;
        As[lc + 2][lr] = (double)a0.z; As[lc + 3][lr] = (double)a0.w;
        Bs[lc + 0][lr] = (double)b0.x; Bs[lc + 1][lr] = (double)b0.y;
        Bs[lc + 2][lr] = (double)b0.z; Bs[lc + 3][lr] = (double)b0.w;
        __syncthreads();
#pragma unroll
        for (int kk = 0; kk < 16; ++kk) {
            double2 a01 = *(const double2*)&As[kk][ty << 2];
            double2 a23 = *(const double2*)&As[kk][(ty << 2) + 2];
            double2 b01 = *(const double2*)&Bs[kk][tx << 2];
            double2 b23 = *(const double2*)&Bs[kk][(tx << 2) + 2];
            double a[4] = {a01.x, a01.y, a23.x, a23.y};
            double b[4] = {b01.x, b01.y, b23.x, b23.y};
#pragma unroll
            for (int i = 0; i < 4; ++i)
#pragma unroll
                for (int j = 0; j < 4; ++j)
                    acc[i][j] += a[i] * b[j];
        }
    }
#pragma unroll
    for (int i = 0; i < 4; ++i) {
        size_t o = (size_t)(m0 + (ty << 2) + i) * 256 + n0 + (tx << 2);
        double2 r0 = {acc[i][0], acc[i][1]};
        double2 r1 = {acc[i][2], acc[i][3]};
        *(double2*)&Cm[o] = r0;
        *(double2*)&Cm[o + 2] = r1;
    }
}

// ------------- pass A: per-chunk KV fp32 (16x64) and Ksum fp64 (16) -------------
__global__ __launch_bounds__(256) void chunk_kv(const double* __restrict__ kg,
                                                const float* __restrict__ vg,
                                                float* __restrict__ KV,
                                                double* __restrict__ Ksum) {
    __shared__ double ksd[CHUNK][16];
    __shared__ float vs[CHUNK][64];
    const int c = blockIdx.x, bh = blockIdx.y;
    const int b = bh >> 4, h = bh & 15;
    const int n0 = b * L_ + c * CHUNK;
    const int tid = threadIdx.x;

    {
        int r = tid >> 1, o = (tid & 1) * 8;
        const double* kp = &kg[(size_t)(n0 + r) * 256 + h * 16 + o];
#pragma unroll
        for (int j = 0; j < 4; ++j)
            *(double2*)&ksd[r][o + j * 2] = *(const double2*)(kp + j * 2);
    }
    {
        int r = tid >> 1, half = (tid & 1) * 32;
        const float* vp = &vg[(size_t)(n0 + r) * 1024 + h * 64 + half];
#pragma unroll
        for (int j = 0; j < 8; ++j)
            *(float4*)&vs[r][half + j * 4] = *(const float4*)(vp + j * 4);
    }
    __syncthreads();

    const int f = tid >> 4;
    const int e4 = tid & 15;
    float a0 = 0.f, a1 = 0.f, a2 = 0.f, a3 = 0.f;
    double ksacc = 0.0;
    for (int l = 0; l < CHUNK; ++l) {
        double kd = ksd[l][f];
        float kv = (float)kd;
        float4 vv = *(const float4*)&vs[l][e4 << 2];
        a0 += kv * vv.x; a1 += kv * vv.y; a2 += kv * vv.z; a3 += kv * vv.w;
        ksacc += kd;
    }
    size_t o = ((size_t)bh * NCH + c) * 1024 + f * 64 + (e4 << 2);
    float4 r = {a0, a1, a2, a3};
    *(float4*)&KV[o] = r;
    if (e4 == 0) Ksum[((size_t)bh * NCH + c) * 16 + f] = ksacc;
}

// ------------- pass B: exclusive prefix over chunks -------------
__global__ __launch_bounds__(256) void prefix_kv(const float* __restrict__ KV,
                                                 const double* __restrict__ Ksum,
                                                 float* __restrict__ KVpre,
                                                 double* __restrict__ Kpre) {
    const int bh = blockIdx.x;
    const int t = threadIdx.x;
    float r0 = 0.f, r1 = 0.f, r2 = 0.f, r3 = 0.f;
    size_t base = (size_t)bh * NCH * 1024 + t * 4;
    for (int c = 0; c < NCH; ++c) {
        float4 w = {r0, r1, r2, r3};
        *(float4*)&KVpre[base + (size_t)c * 1024] = w;
        float4 cur = *(const float4*)&KV[base + (size_t)c * 1024];
        r0 += cur.x; r1 += cur.y; r2 += cur.z; r3 += cur.w;
    }
    if (t < 16) {
        double s = 0.0;
        size_t kb = (size_t)bh * NCH * 16 + t;
        for (int c = 0; c < NCH; ++c) {
            Kpre[kb + (size_t)c * 16] = s;
            s += Ksum[kb + (size_t)c * 16];
        }
    }
}

// ------------- pass C: per-chunk causal attention; writes y pre-split bf16x3 -------------
// Y3 written A-style [hi | lo | hi] (lo at +1024, hi copy at +2048).
__global__ __launch_bounds__(256) void attn_out(const double* __restrict__ qg,
                                                const double* __restrict__ kg,
                                                const float* __restrict__ vg,
                                                const float* __restrict__ kvpre,
                                                const double* __restrict__ kpreg,
                                                ushort* __restrict__ y3) {
    __shared__ double qs[CHUNK][16];
    __shared__ double ks[CHUNK][16];
    __shared__ float vs[CHUNK][64];
    __shared__ float s0[16][64];
    __shared__ double kp[16];
    const int c = blockIdx.x, bh = blockIdx.y;
    const int b = bh >> 4, h = bh & 15;
    const int n0 = b * L_ + c * CHUNK;
    const int tid = threadIdx.x;

    {
        int r = tid >> 1, o = (tid & 1) * 8;
        const double* qp = &qg[(size_t)(n0 + r) * 256 + h * 16 + o];
        const double* kptr = &kg[(size_t)(n0 + r) * 256 + h * 16 + o];
#pragma unroll
        for (int j = 0; j < 4; ++j) {
            *(double2*)&qs[r][o + j * 2] = *(const double2*)(qp + j * 2);
            *(double2*)&ks[r][o + j * 2] = *(const double2*)(kptr + j * 2);
        }
    }
    {
        int r = tid >> 1, half = (tid & 1) * 32;
        const float* vp = &vg[(size_t)(n0 + r) * 1024 + h * 64 + half];
#pragma unroll
        for (int j = 0; j < 8; ++j)
            *(float4*)&vs[r][half + j * 4] = *(const float4*)(vp + j * 4);
    }
    {
        float4 w = *(const float4*)&kvpre[((size_t)bh * NCH + c) * 1024 + tid * 4];
        *(float4*)&s0[0][tid * 4] = w;
        if (tid < 16) kp[tid] = kpreg[((size_t)bh * NCH + c) * 16 + tid];
    }
    __syncthreads();

    const int i = tid >> 1;
    const int half = (tid & 1) * 32;

    double qr[16];
#pragma unroll
    for (int f = 0; f < 16; ++f) qr[f] = qs[i][f];

    double denom = 0.0;
#pragma unroll
    for (int f = 0; f < 16; ++f) denom += qr[f] * kp[f];

    float acc[32] = {};
#pragma unroll
    for (int f = 0; f < 16; ++f) {
        float qf = (float)qr[f];
#pragma unroll
        for (int e = 0; e < 32; e += 4) {
            float4 sv = *(const float4*)&s0[f][half + e];
            acc[e + 0] += qf * sv.x; acc[e + 1] += qf * sv.y;
            acc[e + 2] += qf * sv.z; acc[e + 3] += qf * sv.w;
        }
    }
    for (int j = 0; j <= i; ++j) {
        double s64 = 0.0;
#pragma unroll
        for (int f = 0; f < 16; ++f) s64 += qr[f] * ks[j][f];
        denom += s64;
        float s = (float)s64;
        const float4* vj = (const float4*)&vs[j][half];
#pragma unroll
        for (int e4 = 0; e4 < 8; ++e4) {
            float4 vv = vj[e4];
            acc[e4 * 4 + 0] += s * vv.x; acc[e4 * 4 + 1] += s * vv.y;
            acc[e4 * 4 + 2] += s * vv.z; acc[e4 * 4 + 3] += s * vv.w;
        }
    }

    const float z = (float)(1.0 / (denom + 1e-12));
    ushort* yp = &y3[(size_t)(n0 + i) * K3 + h * 64 + half];
#pragma unroll
    for (int e4 = 0; e4 < 8; ++e4) {
        ushort hs[4], ls[4];
#pragma unroll
        for (int j = 0; j < 4; ++j) {
            float val = acc[e4 * 4 + j] * z;
            ushort hh = bf_rne(val);
            hs[j] = hh;
            ls[j] = bf_rne(val - bf_to_f(hh));
        }
        ushort4 hv = make_ushort4(hs[0], hs[1], hs[2], hs[3]);
        *(ushort4*)(yp + e4 * 4)        = hv;   // hi
        *(ushort4*)(yp + 1024 + e4 * 4) = make_ushort4(ls[0], ls[1], ls[2], ls[3]); // lo
        *(ushort4*)(yp + 2048 + e4 * 4) = hv;   // hi copy
    }
}

extern "C" void kernel_launch(void* const* d_in, const int* in_sizes, int n_in,
                              void* d_out, int out_size, void* d_ws, size_t ws_size,
                              hipStream_t stream) {
    const float* X  = (const float*)d_in[0];
    const float* Wq = (const float*)d_in[1];
    const float* Wk = (const float*)d_in[2];
    const float* Wv = (const float*)d_in[3];
    const float* Wo = (const float*)d_in[4];
    float* out = (float*)d_out;

    double* q64   = (double*)d_ws;                 // 8 MB
    double* k64   = q64 + 1048576;                 // 8 MB
    float*  v     = (float*)(k64 + 1048576);       // 16 MB
    float*  KV    = v + 4194304;                   // 2 MB
    float*  KVpre = KV + 524288;                   // 2 MB
    double* Ksum  = (double*)(KVpre + 524288);     // 64 KB
    double* Kpre  = Ksum + 8192;                   // 64 KB
    ushort* X3    = (ushort*)(Kpre + 8192);        // 24 MB (reused as Y3)
    ushort* Wv3   = X3 + (size_t)4096 * K3;        // 6 MB
    ushort* Wo3   = Wv3 + (size_t)1024 * K3;       // 6 MB
    // total ~72.2 MB

    dim3 blk(256);
    split3<<<2048, blk, 0, stream>>>(X, X3, 4096, 1024, 2048);   // A-style [hi|lo|hi]
    split3<<<512, blk, 0, stream>>>(Wv, Wv3, 1024, 2048, 1024);  // B-style [hi|hi|lo]
    split3<<<512, blk, 0, stream>>>(Wo, Wo3, 1024, 2048, 1024);  // B-style [hi|hi|lo]
    gemm_qk_f64<<<dim3(8, 64), blk, 0, stream>>>(X, Wq, Wk, q64, k64);
    gemm_bf16x3<<<dim3(16, 32), blk, 0, stream>>>(X3, Wv3, v, 1024);
    chunk_kv<<<dim3(NCH, NBH), blk, 0, stream>>>(k64, v, KV, Ksum);
    prefix_kv<<<dim3(NBH), blk, 0, stream>>>(KV, Ksum, KVpre, Kpre);
    attn_out<<<dim3(NCH, NBH), blk, 0, stream>>>(q64, k64, v, KVpre, Kpre, X3);
    gemm_bf16x3<<<dim3(16, 32), blk, 0, stream>>>(X3, Wo3, out, 1024);
}

// Round 12
// 293.665 us; speedup vs baseline: 1.3105x; 1.0282x over previous
//
#include <hip/hip_runtime.h>

// LinearAttention: B=2, L=2048, D=1024, H=16, FD=16, HD=64. fp32 in/out.
// Denominator chain (q,k proj + cumsum + dots) stays fp64 (cancellation,
// z amplifies ~3e4; bf16/MFMA q,k ruled out: fp32 MFMA accumulation error
// ~1e-6 rms -> denom error ~1e-4 vs min|denom| 3e-3 -> fails threshold).
// v-proj/out-proj: bf16x3 MFMA GEMMs (A3=[Ahi|Alo|Ahi], B3=[Bhi|Bhi|Blo]).
// q,k proj: fused vector-fp64 GEMM 64x64/TK=16, f64-staged LDS (cvt-free
// inner loop, R11) + STRIDED fragment mapping (R12): thread covers
// rows {2ty,2ty+1,32+2ty,33+2ty} x cols {2tx,...} so all ds_read_b128 are
// <=2-way (free) — R11's 4x B-read conflict (2.1e7) cost 23% of qk time.
// Lessons: no divergent-body fusion (R8); no split-K atomics (R9); 2
// blocks/CU saturates this loop (R9); check banks when element size changes.

#define L_    2048
#define NROW  4096   // B*L
#define CHUNK 128
#define NCH   16
#define NBH   32
#define K3    3072

#define TM 64
#define TN 64

typedef __attribute__((ext_vector_type(8))) short short8v;
typedef __attribute__((ext_vector_type(4))) float floatx4;

__device__ __forceinline__ ushort bf_rne(float x) {
    unsigned u = __float_as_uint(x);
    return (ushort)((u + 0x7fffu + ((u >> 16) & 1u)) >> 16);
}
__device__ __forceinline__ float bf_to_f(ushort h) {
    return __uint_as_float(((unsigned)h) << 16);
}
__device__ __forceinline__ void gload16(const ushort* g, ushort* l) {
    __builtin_amdgcn_global_load_lds(
        (const __attribute__((address_space(1))) unsigned int*)g,
        (__attribute__((address_space(3))) unsigned int*)l, 16, 0, 0);
}

// ---- split fp32 [rows][1024] -> bf16 [rows][3072]: hi at 0 and hi2_off,
// ---- lo at lo_off.  A-style: lo_off=1024,hi2=2048. B-style: lo_off=2048,hi2=1024.
__global__ __launch_bounds__(256) void split3(const float* __restrict__ in,
                                              ushort* __restrict__ out3, int nrow,
                                              int lo_off, int hi2_off) {
    int idx = blockIdx.x * 256 + threadIdx.x;
    int row = idx >> 7, g = idx & 127;
    if (row >= nrow) return;
    const float* p = in + (size_t)row * 1024 + g * 8;
    float4 x0 = *(const float4*)p, x1 = *(const float4*)(p + 4);
    float xs[8] = {x0.x, x0.y, x0.z, x0.w, x1.x, x1.y, x1.z, x1.w};
    ushort hs[8], ls[8];
#pragma unroll
    for (int j = 0; j < 8; ++j) {
        ushort h = bf_rne(xs[j]);
        hs[j] = h;
        ls[j] = bf_rne(xs[j] - bf_to_f(h));
    }
    ushort* o = out3 + (size_t)row * 3072 + g * 8;
    ushort4 h0 = make_ushort4(hs[0], hs[1], hs[2], hs[3]);
    ushort4 h1 = make_ushort4(hs[4], hs[5], hs[6], hs[7]);
    *(ushort4*)(o)               = h0;
    *(ushort4*)(o + 4)           = h1;
    *(ushort4*)(o + hi2_off)     = h0;
    *(ushort4*)(o + hi2_off + 4) = h1;
    *(ushort4*)(o + lo_off)      = make_ushort4(ls[0], ls[1], ls[2], ls[3]);
    *(ushort4*)(o + lo_off + 4)  = make_ushort4(ls[4], ls[5], ls[6], ls[7]);
}

// -------- bf16 NT GEMM: C[M,1024] f32 = A3[M,3072] @ B3[1024,3072]^T --------
// Tile 128(M)x64(N), BK=64, 4 waves 2x2 (wave = 64x32), dbuf LDS 48KB ->
// 3 blocks/CU, gload_lds w=16, grid (16,32) = 512 blocks. (R10-proven)
__global__ __launch_bounds__(256) void gemm_bf16x3(const ushort* __restrict__ A3,
                                                   const ushort* __restrict__ B3,
                                                   float* __restrict__ Cm, int Nn) {
    __shared__ ushort As[2][8192];
    __shared__ ushort Bs[2][4096];
    const int tid = threadIdx.x;
    const int lane = tid & 63;
    const int wy = tid >> 7;
    const int wx = (tid >> 6) & 1;
    const int m0 = blockIdx.y * 128;
    const int n0 = blockIdx.x * 64;

    const int arow = tid >> 3;                   // 0..31
    const int aslot = (tid & 7) ^ (arow & 7);    // inverse-swizzled source slot
    const ushort* pA[4];
    const ushort* pB[2];
#pragma unroll
    for (int i = 0; i < 4; ++i)
        pA[i] = A3 + (size_t)(m0 + i * 32 + arow) * K3 + aslot * 8;
#pragma unroll
    for (int i = 0; i < 2; ++i)
        pB[i] = B3 + (size_t)(n0 + i * 32 + arow) * K3 + aslot * 8;

#define STAGE(buf, kk)                                              \
    do {                                                            \
        _Pragma("unroll") for (int i = 0; i < 4; ++i)               \
            gload16(pA[i] + (kk), &As[buf][i * 2048 + tid * 8]);    \
        _Pragma("unroll") for (int i = 0; i < 2; ++i)               \
            gload16(pB[i] + (kk), &Bs[buf][i * 2048 + tid * 8]);    \
    } while (0)

    const int abase = (wy * 64 + (lane & 15)) * 64;
    const int bbase = (wx * 32 + (lane & 15)) * 64;

    floatx4 acc[4][2] = {};
    STAGE(0, 0);
    for (int t = 0; t < 48; ++t) {
        const int cur = t & 1;
        __syncthreads();
        if (t < 47) STAGE(1 - cur, (t + 1) * 64);
#pragma unroll
        for (int ksub = 0; ksub < 2; ++ksub) {
            const int so = ((((lane >> 4) | (ksub << 2)) ^ (lane & 7)) << 3);
            short8v a[4], b[2];
#pragma unroll
            for (int mf = 0; mf < 4; ++mf)
                a[mf] = *(const short8v*)&As[cur][abase + mf * 1024 + so];
#pragma unroll
            for (int nf = 0; nf < 2; ++nf)
                b[nf] = *(const short8v*)&Bs[cur][bbase + nf * 1024 + so];
#pragma unroll
            for (int mf = 0; mf < 4; ++mf)
#pragma unroll
                for (int nf = 0; nf < 2; ++nf)
                    acc[mf][nf] = __builtin_amdgcn_mfma_f32_16x16x32_bf16(
                        a[mf], b[nf], acc[mf][nf], 0, 0, 0);
        }
    }
#undef STAGE

#pragma unroll
    for (int mf = 0; mf < 4; ++mf) {
        int row = m0 + wy * 64 + mf * 16 + ((lane >> 4) << 2);
#pragma unroll
        for (int nf = 0; nf < 2; ++nf) {
            int col = n0 + wx * 32 + nf * 16 + (lane & 15);
#pragma unroll
            for (int r = 0; r < 4; ++r)
                Cm[(size_t)(row + r) * Nn + col] = acc[mf][nf][r];
        }
    }
}

// ---- fused q+k fp64 NT GEMM, TK=16, f64-staged LDS, strided fragments ----
// C f64 = X[4096,1024] @ W^T, W = Wq (n0g<256) else Wk. Tile 64x64.
// Thread (ty,tx) owns rows {2ty,2ty+1,32+2ty,33+2ty} x cols {2tx,2tx+1,
// 32+2tx,33+2tx}. All ds_read_b128: A 4-addr broadcast (free), B banks
// 4tx%32 -> 2-way (free). Staging writes 2-way (free). Inner loop pure
// v_fma_f64. Bit-identical output to R10/R11. Grid (8,64) = 512 blocks.
__global__ __launch_bounds__(256) void gemm_qk_f64(const float* __restrict__ X,
                                                   const float* __restrict__ Wq,
                                                   const float* __restrict__ Wk,
                                                   double* __restrict__ q64,
                                                   double* __restrict__ k64) {
    __shared__ __align__(16) double As[16][66];
    __shared__ __align__(16) double Bs[16][66];
    const int tid = threadIdx.x;
    const int m0 = blockIdx.y * TM;
    const int n0g = blockIdx.x * TN;
    const bool isq = n0g < 256;
    const float* Wm = isq ? Wq : Wk;
    double* Cm = isq ? q64 : k64;
    const int n0 = isq ? n0g : n0g - 256;

    const int lr = tid >> 2;          // 0..63 staging row
    const int lc = (tid & 3) << 2;    // staging kk offset 0,4,8,12
    const int ty = tid >> 4;          // 0..15
    const int tx = tid & 15;          // 0..15

    double acc[4][4] = {};
    const float* Ap = X + (size_t)(m0 + lr) * 1024 + lc;
    const float* Bp = Wm + (size_t)(n0 + lr) * 1024 + lc;

    for (int k0 = 0; k0 < 1024; k0 += 16) {
        float4 a0 = *(const float4*)(Ap + k0);
        float4 b0 = *(const float4*)(Bp + k0);
        __syncthreads();
        As[lc + 0][lr] = (double)a0.x; As[lc + 1][lr] = (double)a0.y;
        As[lc + 2][lr] = (double)a0.z; As[lc + 3][lr] = (double)a0.w;
        Bs[lc + 0][lr] = (double)b0.x; Bs[lc + 1][lr] = (double)b0.y;
        Bs[lc + 2][lr] = (double)b0.z; Bs[lc + 3][lr] = (double)b0.w;
        __syncthreads();
#pragma unroll
        for (int kk = 0; kk < 16; ++kk) {
            double2 a0v = *(const double2*)&As[kk][ty << 1];
            double2 a1v = *(const double2*)&As[kk][(ty << 1) + 32];
            double2 b0v = *(const double2*)&Bs[kk][tx << 1];
            double2 b1v = *(const double2*)&Bs[kk][(tx << 1) + 32];
            double a[4] = {a0v.x, a0v.y, a1v.x, a1v.y};
            double b[4] = {b0v.x, b0v.y, b1v.x, b1v.y};
#pragma unroll
            for (int i = 0; i < 4; ++i)
#pragma unroll
                for (int j = 0; j < 4; ++j)
                    acc[i][j] += a[i] * b[j];
        }
    }
#pragma unroll
    for (int i = 0; i < 4; ++i) {
        int row = m0 + ((i >> 1) << 5) + (ty << 1) + (i & 1);
        size_t o = (size_t)row * 256 + n0 + (tx << 1);
        double2 r0 = {acc[i][0], acc[i][1]};
        double2 r1 = {acc[i][2], acc[i][3]};
        *(double2*)&Cm[o] = r0;
        *(double2*)&Cm[o + 32] = r1;
    }
}

// ------------- pass A: per-chunk KV fp32 (16x64) and Ksum fp64 (16) -------------
__global__ __launch_bounds__(256) void chunk_kv(const double* __restrict__ kg,
                                                const float* __restrict__ vg,
                                                float* __restrict__ KV,
                                                double* __restrict__ Ksum) {
    __shared__ double ksd[CHUNK][16];
    __shared__ float vs[CHUNK][64];
    const int c = blockIdx.x, bh = blockIdx.y;
    const int b = bh >> 4, h = bh & 15;
    const int n0 = b * L_ + c * CHUNK;
    const int tid = threadIdx.x;

    {
        int r = tid >> 1, o = (tid & 1) * 8;
        const double* kp = &kg[(size_t)(n0 + r) * 256 + h * 16 + o];
#pragma unroll
        for (int j = 0; j < 4; ++j)
            *(double2*)&ksd[r][o + j * 2] = *(const double2*)(kp + j * 2);
    }
    {
        int r = tid >> 1, half = (tid & 1) * 32;
        const float* vp = &vg[(size_t)(n0 + r) * 1024 + h * 64 + half];
#pragma unroll
        for (int j = 0; j < 8; ++j)
            *(float4*)&vs[r][half + j * 4] = *(const float4*)(vp + j * 4);
    }
    __syncthreads();

    const int f = tid >> 4;
    const int e4 = tid & 15;
    float a0 = 0.f, a1 = 0.f, a2 = 0.f, a3 = 0.f;
    double ksacc = 0.0;
    for (int l = 0; l < CHUNK; ++l) {
        double kd = ksd[l][f];
        float kv = (float)kd;
        float4 vv = *(const float4*)&vs[l][e4 << 2];
        a0 += kv * vv.x; a1 += kv * vv.y; a2 += kv * vv.z; a3 += kv * vv.w;
        ksacc += kd;
    }
    size_t o = ((size_t)bh * NCH + c) * 1024 + f * 64 + (e4 << 2);
    float4 r = {a0, a1, a2, a3};
    *(float4*)&KV[o] = r;
    if (e4 == 0) Ksum[((size_t)bh * NCH + c) * 16 + f] = ksacc;
}

// ------------- pass B: exclusive prefix over chunks -------------
__global__ __launch_bounds__(256) void prefix_kv(const float* __restrict__ KV,
                                                 const double* __restrict__ Ksum,
                                                 float* __restrict__ KVpre,
                                                 double* __restrict__ Kpre) {
    const int bh = blockIdx.x;
    const int t = threadIdx.x;
    float r0 = 0.f, r1 = 0.f, r2 = 0.f, r3 = 0.f;
    size_t base = (size_t)bh * NCH * 1024 + t * 4;
    for (int c = 0; c < NCH; ++c) {
        float4 w = {r0, r1, r2, r3};
        *(float4*)&KVpre[base + (size_t)c * 1024] = w;
        float4 cur = *(const float4*)&KV[base + (size_t)c * 1024];
        r0 += cur.x; r1 += cur.y; r2 += cur.z; r3 += cur.w;
    }
    if (t < 16) {
        double s = 0.0;
        size_t kb = (size_t)bh * NCH * 16 + t;
        for (int c = 0; c < NCH; ++c) {
            Kpre[kb + (size_t)c * 16] = s;
            s += Ksum[kb + (size_t)c * 16];
        }
    }
}

// ------------- pass C: per-chunk causal attention; writes y pre-split bf16x3 -------------
// Y3 written A-style [hi | lo | hi] (lo at +1024, hi copy at +2048).
__global__ __launch_bounds__(256) void attn_out(const double* __restrict__ qg,
                                                const double* __restrict__ kg,
                                                const float* __restrict__ vg,
                                                const float* __restrict__ kvpre,
                                                const double* __restrict__ kpreg,
                                                ushort* __restrict__ y3) {
    __shared__ double qs[CHUNK][16];
    __shared__ double ks[CHUNK][16];
    __shared__ float vs[CHUNK][64];
    __shared__ float s0[16][64];
    __shared__ double kp[16];
    const int c = blockIdx.x, bh = blockIdx.y;
    const int b = bh >> 4, h = bh & 15;
    const int n0 = b * L_ + c * CHUNK;
    const int tid = threadIdx.x;

    {
        int r = tid >> 1, o = (tid & 1) * 8;
        const double* qp = &qg[(size_t)(n0 + r) * 256 + h * 16 + o];
        const double* kptr = &kg[(size_t)(n0 + r) * 256 + h * 16 + o];
#pragma unroll
        for (int j = 0; j < 4; ++j) {
            *(double2*)&qs[r][o + j * 2] = *(const double2*)(qp + j * 2);
            *(double2*)&ks[r][o + j * 2] = *(const double2*)(kptr + j * 2);
        }
    }
    {
        int r = tid >> 1, half = (tid & 1) * 32;
        const float* vp = &vg[(size_t)(n0 + r) * 1024 + h * 64 + half];
#pragma unroll
        for (int j = 0; j < 8; ++j)
            *(float4*)&vs[r][half + j * 4] = *(const float4*)(vp + j * 4);
    }
    {
        float4 w = *(const float4*)&kvpre[((size_t)bh * NCH + c) * 1024 + tid * 4];
        *(float4*)&s0[0][tid * 4] = w;
        if (tid < 16) kp[tid] = kpreg[((size_t)bh * NCH + c) * 16 + tid];
    }
    __syncthreads();

    const int i = tid >> 1;
    const int half = (tid & 1) * 32;

    double qr[16];
#pragma unroll
    for (int f = 0; f < 16; ++f) qr[f] = qs[i][f];

    double denom = 0.0;
#pragma unroll
    for (int f = 0; f < 16; ++f) denom += qr[f] * kp[f];

    float acc[32] = {};
#pragma unroll
    for (int f = 0; f < 16; ++f) {
        float qf = (float)qr[f];
#pragma unroll
        for (int e = 0; e < 32; e += 4) {
            float4 sv = *(const float4*)&s0[f][half + e];
            acc[e + 0] += qf * sv.x; acc[e + 1] += qf * sv.y;
            acc[e + 2] += qf * sv.z; acc[e + 3] += qf * sv.w;
        }
    }
    for (int j = 0; j <= i; ++j) {
        double s64 = 0.0;
#pragma unroll
        for (int f = 0; f < 16; ++f) s64 += qr[f] * ks[j][f];
        denom += s64;
        float s = (float)s64;
        const float4* vj = (const float4*)&vs[j][half];
#pragma unroll
        for (int e4 = 0; e4 < 8; ++e4) {
            float4 vv = vj[e4];
            acc[e4 * 4 + 0] += s * vv.x; acc[e4 * 4 + 1] += s * vv.y;
            acc[e4 * 4 + 2] += s * vv.z; acc[e4 * 4 + 3] += s * vv.w;
        }
    }

    const float z = (float)(1.0 / (denom + 1e-12));
    ushort* yp = &y3[(size_t)(n0 + i) * K3 + h * 64 + half];
#pragma unroll
    for (int e4 = 0; e4 < 8; ++e4) {
        ushort hs[4], ls[4];
#pragma unroll
        for (int j = 0; j < 4; ++j) {
            float val = acc[e4 * 4 + j] * z;
            ushort hh = bf_rne(val);
            hs[j] = hh;
            ls[j] = bf_rne(val - bf_to_f(hh));
        }
        ushort4 hv = make_ushort4(hs[0], hs[1], hs[2], hs[3]);
        *(ushort4*)(yp + e4 * 4)        = hv;   // hi
        *(ushort4*)(yp + 1024 + e4 * 4) = make_ushort4(ls[0], ls[1], ls[2], ls[3]); // lo
        *(ushort4*)(yp + 2048 + e4 * 4) = hv;   // hi copy
    }
}

extern "C" void kernel_launch(void* const* d_in, const int* in_sizes, int n_in,
                              void* d_out, int out_size, void* d_ws, size_t ws_size,
                              hipStream_t stream) {
    const float* X  = (const float*)d_in[0];
    const float* Wq = (const float*)d_in[1];
    const float* Wk = (const float*)d_in[2];
    const float* Wv = (const float*)d_in[3];
    const float* Wo = (const float*)d_in[4];
    float* out = (float*)d_out;

    double* q64   = (double*)d_ws;                 // 8 MB
    double* k64   = q64 + 1048576;                 // 8 MB
    float*  v     = (float*)(k64 + 1048576);       // 16 MB
    float*  KV    = v + 4194304;                   // 2 MB
    float*  KVpre = KV + 524288;                   // 2 MB
    double* Ksum  = (double*)(KVpre + 524288);     // 64 KB
    double* Kpre  = Ksum + 8192;                   // 64 KB
    ushort* X3    = (ushort*)(Kpre + 8192);        // 24 MB (reused as Y3)
    ushort* Wv3   = X3 + (size_t)4096 * K3;        // 6 MB
    ushort* Wo3   = Wv3 + (size_t)1024 * K3;       // 6 MB
    // total ~72.2 MB

    dim3 blk(256);
    split3<<<2048, blk, 0, stream>>>(X, X3, 4096, 1024, 2048);   // A-style [hi|lo|hi]
    split3<<<512, blk, 0, stream>>>(Wv, Wv3, 1024, 2048, 1024);  // B-style [hi|hi|lo]
    split3<<<512, blk, 0, stream>>>(Wo, Wo3, 1024, 2048, 1024);  // B-style [hi|hi|lo]
    gemm_qk_f64<<<dim3(8, 64), blk, 0, stream>>>(X, Wq, Wk, q64, k64);
    gemm_bf16x3<<<dim3(16, 32), blk, 0, stream>>>(X3, Wv3, v, 1024);
    chunk_kv<<<dim3(NCH, NBH), blk, 0, stream>>>(k64, v, KV, Ksum);
    prefix_kv<<<dim3(NBH), blk, 0, stream>>>(KV, Ksum, KVpre, Kpre);
    attn_out<<<dim3(NCH, NBH), blk, 0, stream>>>(q64, k64, v, KVpre, Kpre, X3);
    gemm_bf16x3<<<dim3(16, 32), blk, 0, stream>>>(X3, Wo3, out, 1024);
}